// Round 2
// baseline (448.729 us; speedup 1.0000x reference)
//
#include <hip/hip_runtime.h>

#define NPTS 400000
#define KOFF 27

typedef __attribute__((ext_vector_type(8))) __bf16 bf16x8;
typedef __attribute__((ext_vector_type(16))) float v16f;

__device__ __forceinline__ float bf2f(unsigned short u) {
  union { unsigned int i; float f; } v; v.i = ((unsigned int)u) << 16; return v.f;
}
__device__ __forceinline__ unsigned short f2bf(float f) {
  union { float f; unsigned int i; } v; v.f = f;
  unsigned int x = v.i;
  return (unsigned short)((x + 0x7FFFu + ((x >> 16) & 1u)) >> 16);  // RNE
}

// ---------------------------------------------------------------- prep: feats -> bf16 table (+zero sentinel rows, zero stats)
__global__ void prep_feats(const float* __restrict__ feats, unsigned short* __restrict__ Xb,
                           unsigned short* __restrict__ H1, float* __restrict__ statszero) {
  int idx = blockIdx.x * 256 + threadIdx.x;          // 6250*256 = 1.6M = NPTS*32/8
  const float4* f4 = (const float4*)feats;
  float4 a = f4[2 * idx], b = f4[2 * idx + 1];
  union { unsigned short u[8]; uint4 v; } p;
  p.u[0] = f2bf(a.x); p.u[1] = f2bf(a.y); p.u[2] = f2bf(a.z); p.u[3] = f2bf(a.w);
  p.u[4] = f2bf(b.x); p.u[5] = f2bf(b.y); p.u[6] = f2bf(b.z); p.u[7] = f2bf(b.w);
  ((uint4*)Xb)[idx] = p.v;
  if (blockIdx.x == 0) {
    if (threadIdx.x < 32) {                           // zero sentinel row N in both gatherable tables
      Xb[(size_t)NPTS * 32 + threadIdx.x] = 0;
      H1[(size_t)NPTS * 32 + threadIdx.x] = 0;
    }
    if (threadIdx.x < 128) statszero[threadIdx.x] = 0.f;  // stats1[64] + stats2[64] contiguous
  }
}

// ---------------------------------------------------------------- prep: masked+transposed neighbor table
// mask arrives as int32 (harness converts jnp bool -> int per "integer -> const int*")
__global__ void prep_nbr(const int* __restrict__ nbr, const int* __restrict__ mask,
                         int* __restrict__ nbrT) {
  int n = blockIdx.x * 256 + threadIdx.x;
  if (n >= NPTS) return;
  #pragma unroll
  for (int k = 0; k < KOFF; ++k) {
    int j = nbr[(size_t)n * KOFF + k];
    int m = mask[(size_t)n * KOFF + k];
    nbrT[(size_t)k * NPTS + n] = (m != 0) ? j : NPTS;  // sentinel -> zero row
  }
}

// ---------------------------------------------------------------- prep: W[k][i][o] -> WT[k][o][i] bf16 (B-fragment friendly)
__global__ void prep_w(const float* __restrict__ W1, const float* __restrict__ W2,
                       unsigned short* __restrict__ WT1, unsigned short* __restrict__ WT2) {
  int i = blockIdx.x * 256 + threadIdx.x;
  if (i >= 27 * 1024) return;
  int k = i >> 10, r = i & 1023, o = r >> 5, ic = r & 31;
  int src = k * 1024 + ic * 32 + o;
  WT1[i] = f2bf(W1[src]);
  WT2[i] = f2bf(W2[src]);
}

// ---------------------------------------------------------------- sparse conv via MFMA; wave = 32 points x 32 outputs
__global__ __launch_bounds__(256, 4) void conv_mfma(
    const unsigned short* __restrict__ X,    // (NPTS+1) x 32 bf16, row NPTS = zeros
    const int* __restrict__ nbrT,            // [27][NPTS] masked neighbor rows
    const unsigned short* __restrict__ WT,   // [27][32 o][32 i] bf16
    unsigned short* __restrict__ Hout,       // [NPTS][32] bf16 raw conv output
    float* __restrict__ stats)               // [64]: 0..31 sum, 32..63 sumsq
{
  const int lane = threadIdx.x & 63;
  const int wv   = threadIdx.x >> 6;         // 0..3
  const int col  = lane & 31;                // point index (A side) / output channel (B/D side)
  const int hf   = lane >> 5;                // which 8-wide K chunk this lane holds
  const int n0   = (blockIdx.x * 4 + wv) * 32;

  v16f acc;
  #pragma unroll
  for (int i = 0; i < 16; ++i) acc[i] = 0.0f;

  const int* nb = nbrT + n0 + col;
  const bf16x8* wp = (const bf16x8*)(WT + col * 32 + hf * 8);

  #pragma unroll 4
  for (int k = 0; k < KOFF; ++k) {
    int row = nb[k * NPTS];                                  // coalesced (lanes 0..31 consecutive)
    const bf16x8* ap = (const bf16x8*)(X + (size_t)row * 32 + hf * 8);
    bf16x8 a0 = ap[0];                                       // channels  hf*8 .. hf*8+7
    bf16x8 a1 = ap[2];                                       // channels 16+hf*8 ..
    bf16x8 b0 = wp[k * 128];                                 // WT[k][col][ hf*8 ..]
    bf16x8 b1 = wp[k * 128 + 2];                             // WT[k][col][16+hf*8 ..]
    acc = __builtin_amdgcn_mfma_f32_32x32x16_bf16(a0, b0, acc, 0, 0, 0);
    acc = __builtin_amdgcn_mfma_f32_32x32x16_bf16(a1, b1, acc, 0, 0, 0);
  }

  // epilogue: store bf16 + accumulate BN stats
  float s = 0.f, q = 0.f;
  #pragma unroll
  for (int r = 0; r < 16; ++r) {
    float v = acc[r];
    s += v; q += v * v;
    int rw = (r & 3) + 8 * (r >> 2) + 4 * hf;                // verified C/D row mapping (m74/m101)
    Hout[(size_t)(n0 + rw) * 32 + col] = f2bf(v);
  }
  s += __shfl_xor(s, 32);
  q += __shfl_xor(q, 32);
  __shared__ float redS[4][32];
  __shared__ float redQ[4][32];
  if (lane < 32) { redS[wv][col] = s; redQ[wv][col] = q; }
  __syncthreads();
  if (threadIdx.x < 64) {
    int t = threadIdx.x & 31;
    float v = (threadIdx.x < 32)
      ? (redS[0][t] + redS[1][t] + redS[2][t] + redS[3][t])
      : (redQ[0][t] + redQ[1][t] + redQ[2][t] + redQ[3][t]);
    atomicAdd(&stats[threadIdx.x], v);
  }
}

// ---------------------------------------------------------------- BN finalize: stats -> per-channel scale/bias
__global__ void finalize_bn(const float* __restrict__ stats, const float* __restrict__ gamma,
                            const float* __restrict__ beta, float* __restrict__ sb) {
  int t = threadIdx.x;
  if (t < 32) {
    float mean = stats[t] * (1.f / NPTS);
    float var  = stats[t + 32] * (1.f / NPTS) - mean * mean;
    float rstd = rsqrtf(var + 1e-5f);
    float sc = gamma[t] * rstd;
    sb[t] = sc;
    sb[t + 32] = beta[t] - mean * sc;
  }
}

// ---------------------------------------------------------------- BN + ReLU in place (bf16), rows 0..N-1 only
__global__ void bn_relu_inplace(unsigned short* __restrict__ H, const float* __restrict__ sb) {
  int idx = blockIdx.x * 256 + threadIdx.x;          // 1.6M
  uint4 v = ((uint4*)H)[idx];
  union { uint4 v; unsigned short u[8]; } p; p.v = v;
  int baseo = (idx * 8) & 31;
  #pragma unroll
  for (int j = 0; j < 8; ++j) {
    float f = bf2f(p.u[j]);
    f = fmaxf(f * sb[baseo + j] + sb[32 + baseo + j], 0.f);
    p.u[j] = f2bf(f);
  }
  ((uint4*)H)[idx] = p.v;
}

// ---------------------------------------------------------------- BN + residual + ReLU -> fp32 out
__global__ void bn_res_relu_out(const unsigned short* __restrict__ H2, const float* __restrict__ feats,
                                const float* __restrict__ sb, float* __restrict__ out) {
  int idx = blockIdx.x * 256 + threadIdx.x;          // 1.6M
  uint4 v = ((const uint4*)H2)[idx];
  union { uint4 v; unsigned short u[8]; } p; p.v = v;
  int baseo = (idx * 8) & 31;
  const float4* f4 = (const float4*)feats;
  float4 fa = f4[2 * idx], fb = f4[2 * idx + 1];
  float4 o0, o1;
  float* fav = (float*)&fa; float* fbv = (float*)&fb;
  float* o0v = (float*)&o0; float* o1v = (float*)&o1;
  #pragma unroll
  for (int j = 0; j < 4; ++j)
    o0v[j] = fmaxf(bf2f(p.u[j]) * sb[baseo + j] + sb[32 + baseo + j] + fav[j], 0.f);
  #pragma unroll
  for (int j = 0; j < 4; ++j)
    o1v[j] = fmaxf(bf2f(p.u[4 + j]) * sb[baseo + 4 + j] + sb[32 + baseo + 4 + j] + fbv[j], 0.f);
  ((float4*)out)[2 * idx] = o0;
  ((float4*)out)[2 * idx + 1] = o1;
}

// ----------------------------------------------------------------
extern "C" void kernel_launch(void* const* d_in, const int* in_sizes, int n_in,
                              void* d_out, int out_size, void* d_ws, size_t ws_size,
                              hipStream_t stream) {
  const float* feats  = (const float*)d_in[0];
  const float* W1     = (const float*)d_in[1];
  const float* gamma1 = (const float*)d_in[2];
  const float* beta1  = (const float*)d_in[3];
  const float* W2     = (const float*)d_in[4];
  const float* gamma2 = (const float*)d_in[5];
  const float* beta2  = (const float*)d_in[6];
  const int*   nbr    = (const int*)d_in[7];
  const int*   mask   = (const int*)d_in[8];   // jnp bool uploaded as int32 per harness contract

  char* ws = (char*)d_ws;
  const size_t XB = ((size_t)(NPTS + 1) * 32 * 2 + 255) & ~(size_t)255;  // bf16 table w/ sentinel row
  unsigned short* Xb   = (unsigned short*)(ws);
  unsigned short* H1   = (unsigned short*)(ws + XB);
  int*            nbrT = (int*)(ws + 2 * XB);
  size_t off = 2 * XB + (size_t)KOFF * NPTS * 4;
  unsigned short* WT1 = (unsigned short*)(ws + off); off += 27 * 1024 * 2;
  unsigned short* WT2 = (unsigned short*)(ws + off); off += 27 * 1024 * 2;
  float* stats1 = (float*)(ws + off); off += 256;
  float* stats2 = (float*)(ws + off); off += 256;
  float* sb1    = (float*)(ws + off); off += 256;
  float* sb2    = (float*)(ws + off); off += 256;
  unsigned short* H2 = Xb;   // overlay: Xb is dead after conv1

  prep_feats<<<6250, 256, 0, stream>>>(feats, Xb, H1, stats1);   // also zeros stats1+stats2
  prep_nbr<<<1563, 256, 0, stream>>>(nbr, mask, nbrT);
  prep_w<<<108, 256, 0, stream>>>(W1, W2, WT1, WT2);

  conv_mfma<<<3125, 256, 0, stream>>>(Xb, nbrT, WT1, H1, stats1);
  finalize_bn<<<1, 64, 0, stream>>>(stats1, gamma1, beta1, sb1);
  bn_relu_inplace<<<6250, 256, 0, stream>>>(H1, sb1);

  conv_mfma<<<3125, 256, 0, stream>>>(H1, nbrT, WT2, H2, stats2);
  finalize_bn<<<1, 64, 0, stream>>>(stats2, gamma2, beta2, sb2);
  bn_res_relu_out<<<6250, 256, 0, stream>>>(H2, feats, sb2, (float*)d_out);
}